// Round 6
// baseline (7588.296 us; speedup 1.0000x reference)
//
#include <hip/hip_runtime.h>

typedef unsigned int u32;
typedef unsigned short u16;
typedef __attribute__((ext_vector_type(8))) short short8;
typedef __attribute__((ext_vector_type(4))) float f4;

#define MFMA16 __builtin_amdgcn_mfma_f32_16x16x32_bf16
#define ALOAD(p)    __hip_atomic_load((p), __ATOMIC_RELAXED, __HIP_MEMORY_SCOPE_AGENT)
#define ASTORE(p,v) __hip_atomic_store((p), (v), __ATOMIC_RELAXED, __HIP_MEMORY_SCOPE_AGENT)

// ---------- workspace layout (bytes) ----------
#define OFF_XB    0LL            // x bf16       (67,108,864)  [aliased: h0f fp32 after scans]
#define OFF_XD2   67108864LL     // x[::2] bf16  (33,554,432)  [aliased: ln bf16 after scans]
#define OFF_XD4   100663296LL    // x[::4] bf16  (16,777,216)
#define OFF_HCAT  117440512LL    // concat bf16  (234,881,024)
#define OFF_Y     352321536LL    // block GRU out bf16 (33,554,432)
#define OFF_H1    385875968LL    // residual h1 fp32 (67,108,864)
#define OFF_D0WF  452984832LL    // folded d0 weight bf16 (229,376)
#define OFF_HB0   453214208LL    // gru0 h bcast: 2 par x 8 g x 16 x 512 bf16 = 262,144
#define OFF_HB1   453476352LL    // gru1 h bcast: 2 par x 4 g x 32 x 256 bf16 = 131,072
#define OFF_CNT   453607424LL    // barrier counters (1,024)
#define WS_TOTAL  453608448LL

__device__ __forceinline__ u16 f2bf(float f) {
  u32 u = __float_as_uint(f);
  return (u16)((u + 0x7fffu + ((u >> 16) & 1u)) >> 16);   // RNE
}
__device__ __forceinline__ float bf2f(u32 b) { return __uint_as_float(b << 16); }
__device__ __forceinline__ float sigm(float x) { return __builtin_amdgcn_rcpf(1.f + __expf(-x)); }
__device__ __forceinline__ float tanh_(float x) { return 1.f - 2.f * __builtin_amdgcn_rcpf(1.f + __expf(2.f * x)); }

__device__ __forceinline__ short8 cvt8(const float* p) {
  short8 r;
#pragma unroll
  for (int j = 0; j < 8; ++j) r[j] = (short)f2bf(p[j]);
  return r;
}

// =====================================================================
// Generic fused GRU scan (round-2 proven form; wave-role branches
// SCALARIZED via readfirstlane — MFMA ignores EXEC, so if-converted role
// branches corrupt accumulators). PITCH padded +32 B so row bank windows
// rotate (stride mod 128 != 0) — kills the 16-row bank aliasing.
// =====================================================================
template<int KH, int KX, int BT, int CSPAN, int WAVES, int GROUP_WGS>
__device__ __forceinline__ void gru_scan(
    const float* __restrict__ wih, const float* __restrict__ whh,
    const float* __restrict__ bih, const float* __restrict__ bhh,
    const u16* __restrict__ xsrc,                     // [S*128][KX] bf16
    u16* __restrict__ outp, const int outPitch, const int outColBase,
    const int group, const int slab,
    u32* __restrict__ hbA, u32* __restrict__ hbB, u32* __restrict__ cnt,
    char* sm)
{
  constexpr int H = KH;
  constexpr int KT = (KH + KX) / 32;
  constexpr int KH32 = KH / 32;
  constexpr int PITCH = (KH + KX) * 2 + 32;  // +32: rotate bank window per row
  constexpr int CT_N = CSPAN / 16;
  constexpr int NTILES = (BT / 16) * CT_N;
  constexpr int MAXP = (NTILES + WAVES - 1) / WAVES;
  constexpr int NT = WAVES * 64;
  constexpr int NX = (BT * KX / 2) / NT;     // x dwords per thread
  constexpr int NH = (BT * KH / 2) / NT;     // h dwords per thread (GH only)
  constexpr bool GH = (GROUP_WGS > 0);

  const int tid = threadIdx.x;
  const int l = tid & 63;
  const int wv = __builtin_amdgcn_readfirstlane(tid >> 6);  // SCALAR wave id
  const int lr = l & 15;   // fragment row/col lane index
  const int lh = l >> 4;   // k-chunk
  const long srow0 = group * BT;

  // ---- load weight B-fragments into registers (once) ----
  short8 Br[MAXP][KT], Bz[MAXP][KT], Bn[MAXP][KT];
  float bb0[MAXP], bb1[MAXP], bb2[MAXP], bb3[MAXP];
  float hk[MAXP][4];
#pragma unroll
  for (int p = 0; p < MAXP; ++p) {
    const int tp = wv + WAVES * p;
    const int tpc = (tp < NTILES) ? tp : 0;
    const int ct = tpc % CT_N;
    const int gcol = slab * CSPAN + ct * 16 + lr;   // column within H
#pragma unroll
    for (int t = 0; t < KT; ++t) {
      const int k = t * 32 + lh * 8;
      if (t < KH32) {
        Br[p][t] = cvt8(whh + (long)(0 * H + gcol) * KH + k);
        Bz[p][t] = cvt8(whh + (long)(1 * H + gcol) * KH + k);
        Bn[p][t] = cvt8(whh + (long)(2 * H + gcol) * KH + k);
      } else {
        const int kx = k - KH;
        Br[p][t] = cvt8(wih + (long)(0 * H + gcol) * KX + kx);
        Bz[p][t] = cvt8(wih + (long)(1 * H + gcol) * KX + kx);
        Bn[p][t] = cvt8(wih + (long)(2 * H + gcol) * KX + kx);
      }
    }
    bb0[p] = bih[0 * H + gcol] + bhh[0 * H + gcol];
    bb1[p] = bih[1 * H + gcol] + bhh[1 * H + gcol];
    bb2[p] = bih[2 * H + gcol];   // input-side n bias
    bb3[p] = bhh[2 * H + gcol];   // hidden-side n bias
    hk[p][0] = hk[p][1] = hk[p][2] = hk[p][3] = 0.f;
  }

  // ---- zero local h region (h0 = 0) ----
  if constexpr (!GH) {
#pragma unroll
    for (int i = 0; i < (BT * KH / 2 + NT - 1) / NT; ++i) {
      const int idx = tid + NT * i;
      if (idx < BT * KH / 2) {
        const int r = idx / (KH / 2), d = idx % (KH / 2);
        *(u32*)(sm + r * PITCH + ((d * 4) ^ ((r & 7) << 4))) = 0u;
      }
    }
  }

  // ---- prefetch x for step 0 ----
  u32 xr[NX];
#pragma unroll
  for (int i = 0; i < NX; ++i) {
    const int idx = tid + NT * i;
    const int r = idx / (KX / 2), d = idx % (KX / 2);
    xr[i] = *(const u32*)(xsrc + (srow0 + r) * KX + d * 2);
  }

  for (int s = 0; s < 1024; ++s) {
    // ---- stage x part of A-tile (from prefetched regs) ----
#pragma unroll
    for (int i = 0; i < NX; ++i) {
      const int idx = tid + NT * i;
      const int r = idx / (KX / 2), d = idx % (KX / 2);
      *(u32*)(sm + r * PITCH + ((KH * 2 + d * 4) ^ ((r & 7) << 4))) = xr[i];
    }
    // ---- stage h part (coherent loads from peer WGs' stores) ----
    if constexpr (GH) {
      const u32* hb = (s & 1) ? hbB : hbA;
#pragma unroll
      for (int i = 0; i < NH; ++i) {
        const int idx = tid + NT * i;
        const int r = idx / (KH / 2), d = idx % (KH / 2);
        const u32 v = ALOAD(hb + r * (KH / 2) + d);
        *(u32*)(sm + r * PITCH + ((d * 4) ^ ((r & 7) << 4))) = v;
      }
    }
    // ---- prefetch next x (hides under MFMA) ----
    if (s + 1 < 1024) {
#pragma unroll
      for (int i = 0; i < NX; ++i) {
        const int idx = tid + NT * i;
        const int r = idx / (KX / 2), d = idx % (KX / 2);
        xr[i] = *(const u32*)(xsrc + ((s + 1) * 128L + srow0 + r) * KX + d * 2);
      }
    }
    __syncthreads();

    // ---- per-wave gate-triple MFMA (4 chains: r, z, n_h, n_x) ----
    u32 hnew[MAXP][4];
#pragma unroll
    for (int p = 0; p < MAXP; ++p) {
      const int tp = wv + WAVES * p;            // scalar
      if (tp < NTILES) {                        // scalar branch -> s_cbranch
        const int mt = tp / CT_N;
        f4 ar = {0.f, 0.f, 0.f, 0.f}; f4 az = ar, anh = ar, anx = ar;
#pragma unroll
        for (int t = 0; t < KT; ++t) {
          const int row = mt * 16 + lr;
          const short8 a = *(const short8*)(sm + row * PITCH +
                              ((t * 64 + lh * 16) ^ ((row & 7) << 4)));
          ar = MFMA16(a, Br[p][t], ar, 0, 0, 0);
          az = MFMA16(a, Bz[p][t], az, 0, 0, 0);
          if (t < KH32) anh = MFMA16(a, Bn[p][t], anh, 0, 0, 0);
          else          anx = MFMA16(a, Bn[p][t], anx, 0, 0, 0);
        }
#pragma unroll
        for (int q = 0; q < 4; ++q) {
          const float rg = sigm(ar[q] + bb0[p]);
          const float zg = sigm(az[q] + bb1[p]);
          const float ng = tanh_(anx[q] + bb2[p] + rg * (anh[q] + bb3[p]));
          const float h = (1.f - zg) * ng + zg * hk[p][q];   // fp32 carry
          hk[p][q] = h;
          hnew[p][q] = f2bf(h);
        }
      }
    }
    if constexpr (!GH) __syncthreads();   // A-tile reads done before local h rewrite

    // ---- write h_new: output buffer + (broadcast | local LDS) ----
#pragma unroll
    for (int p = 0; p < MAXP; ++p) {
      const int tp = wv + WAVES * p;            // scalar
      if (tp < NTILES) {
        const int mt = tp / CT_N, ct = tp % CT_N;
        const int c = ct * 16 + lr;
#pragma unroll
        for (int q = 0; q < 4; ++q) {
          const u32 nb = (u32)__shfl_xor((int)hnew[p][q], 1);
          if ((l & 1) == 0) {                       // even lane packs (c, c+1)
            const u32 pk = (hnew[p][q] & 0xffffu) | (nb << 16);
            const int b = mt * 16 + lh * 4 + q;     // C layout: row=(l>>4)*4+q, col=l&15
            *(u32*)(outp + (s * 128L + srow0 + b) * outPitch + outColBase + c) = pk;
            if constexpr (GH) {
              u32* hbn = ((s + 1) & 1) ? hbB : hbA;
              ASTORE(hbn + b * (KH / 2) + (slab * CSPAN + c) / 2, pk);
            } else {
              *(u32*)(sm + b * PITCH + ((c * 2) ^ ((b & 7) << 4))) = pk;
            }
          }
        }
      }
    }
    // ---- per-group step barrier (round-2 proven form) ----
    if constexpr (GH) {
      asm volatile("s_waitcnt vmcnt(0)" ::: "memory");  // h stores + staging loads ack'd
      __syncthreads();
      if (tid == 0) {
        __hip_atomic_fetch_add(cnt, 1u, __ATOMIC_RELAXED, __HIP_MEMORY_SCOPE_AGENT);
        const u32 target = (u32)GROUP_WGS * (u32)(s + 1);
        while (ALOAD(cnt) < target) __builtin_amdgcn_s_sleep(1);
      }
      __syncthreads();
    }
  }
}

// =====================================================================
// gru0 (H=512, Kin=256): GATE-SPLIT scan (round-5 proven math):
//   gg0 (waves 0-3): r (24 t) + n h-part (16 t) -> gates + stores;
//   gg1 (waves 4-7): z (24 t) + n x-part (8 t) -> export via LDS.
// Weight frame 160 VGPR; amdgpu_waves_per_eu(2,2) on the kernel keeps it
// register-resident (round-5 VGPR_Count=128 proved the allocator was
// spilling/remat'ing it per step at ~4.6 us/step).
// PITCH 1568 (= 1536+32) rotates bank windows across rows.
// =====================================================================
__device__ __forceinline__ void gru0_scan(
    const float* __restrict__ wih, const float* __restrict__ whh,
    const float* __restrict__ bih, const float* __restrict__ bhh,
    const u16* __restrict__ x, u16* __restrict__ outp,
    const int group, const int slab,
    u32* __restrict__ hbA, u32* __restrict__ hbB, u32* __restrict__ cnt,
    char* sm)
{
  constexpr int PITCH = 1568;                // (512+256)*2 + 32 pad
  const int tid = threadIdx.x;
  const int l = tid & 63;
  const int wv = __builtin_amdgcn_readfirstlane(tid >> 6);  // SCALAR
  const int lr = l & 15, lh = l >> 4;
  const int ct = wv & 3, gg = wv >> 2;       // scalar role ids
  const long srow0 = group * 16;
  const int gcol = slab * 64 + ct * 16 + lr;
  f4* red = (f4*)(sm + 25088);               // after 16*1568 tile; 8 KB

  // ---- weights: W0 = full-K gate (gg0: r, gg1: z); W1 = n-gate part ----
  short8 W0[24], W1[16];
#pragma unroll
  for (int t = 0; t < 24; ++t) {
    const int k = t * 32 + lh * 8;
    if (t < 16) W0[t] = cvt8(whh + (long)(gg * 512 + gcol) * 512 + k);
    else        W0[t] = cvt8(wih + (long)(gg * 512 + gcol) * 256 + (k - 512));
  }
  if (gg == 0) {
#pragma unroll
    for (int t = 0; t < 16; ++t)
      W1[t] = cvt8(whh + (long)(2 * 512 + gcol) * 512 + t * 32 + lh * 8);
  } else {
#pragma unroll
    for (int t = 0; t < 8; ++t)
      W1[t] = cvt8(wih + (long)(2 * 512 + gcol) * 256 + t * 32 + lh * 8);
  }
  const float bb0 = bih[0 * 512 + gcol] + bhh[0 * 512 + gcol];
  const float bb1 = bih[1 * 512 + gcol] + bhh[1 * 512 + gcol];
  const float bb2 = bih[2 * 512 + gcol];
  const float bb3 = bhh[2 * 512 + gcol];
  float hk[4] = {0.f, 0.f, 0.f, 0.f};

  u32 xr[4];                                 // x prefetch: 2048 dw / 512 thr
#pragma unroll
  for (int i = 0; i < 4; ++i) {
    const int idx = tid + 512 * i;
    const int r = idx >> 7, d = idx & 127;
    xr[i] = *(const u32*)(x + (srow0 + r) * 256 + d * 2);
  }

  for (int s = 0; s < 1024; ++s) {
    // stage x (regs -> LDS, bytes [1024,1536) of each row)
#pragma unroll
    for (int i = 0; i < 4; ++i) {
      const int idx = tid + 512 * i;
      const int r = idx >> 7, d = idx & 127;
      *(u32*)(sm + r * PITCH + ((1024 + d * 4) ^ ((r & 7) << 4))) = xr[i];
    }
    // stage h (full 512 cols from group broadcast)
    {
      const u32* hb = (s & 1) ? hbB : hbA;
#pragma unroll
      for (int i = 0; i < 8; ++i) {
        const int idx = tid + 512 * i;
        const int r = idx >> 8, d = idx & 255;
        const u32 v = ALOAD(hb + r * 256 + d);
        *(u32*)(sm + r * PITCH + ((d * 4) ^ ((r & 7) << 4))) = v;
      }
    }
    if (s + 1 < 1024) {
#pragma unroll
      for (int i = 0; i < 4; ++i) {
        const int idx = tid + 512 * i;
        const int r = idx >> 7, d = idx & 127;
        xr[i] = *(const u32*)(x + ((s + 1) * 128L + srow0 + r) * 256 + d * 2);
      }
    }
    __syncthreads();

    // ---- two chains per wave; scalar role branches around MFMA ----
    f4 a0 = {0.f, 0.f, 0.f, 0.f}, a1 = a0;
    if (gg == 0) {                            // a0 = ar (24 t), a1 = anh (16 t)
#pragma unroll
      for (int t = 0; t < 24; ++t) {
        const short8 a = *(const short8*)(sm + lr * PITCH +
                            ((t * 64 + lh * 16) ^ ((lr & 7) << 4)));
        a0 = MFMA16(a, W0[t], a0, 0, 0, 0);
        if (t < 16) a1 = MFMA16(a, W1[t], a1, 0, 0, 0);
      }
    } else {                                  // a0 = az (24 t), a1 = anx (8 t)
#pragma unroll
      for (int t = 0; t < 24; ++t) {
        const short8 a = *(const short8*)(sm + lr * PITCH +
                            ((t * 64 + lh * 16) ^ ((lr & 7) << 4)));
        a0 = MFMA16(a, W0[t], a0, 0, 0, 0);
        if (t >= 16) a1 = MFMA16(a, W1[t - 16], a1, 0, 0, 0);
      }
      red[(ct * 2 + 0) * 64 + l] = a0;        // az
      red[(ct * 2 + 1) * 64 + l] = a1;        // anx
    }
    __syncthreads();
    if (gg == 0) {                            // combine + gates + store
      const f4 paz  = red[(ct * 2 + 0) * 64 + l];
      const f4 panx = red[(ct * 2 + 1) * 64 + l];
      u32 hnew[4];
#pragma unroll
      for (int q = 0; q < 4; ++q) {
        const float rg = sigm(a0[q] + bb0);
        const float zg = sigm(paz[q] + bb1);
        const float ng = tanh_(panx[q] + bb2 + rg * (a1[q] + bb3));
        const float h = (1.f - zg) * ng + zg * hk[q];
        hk[q] = h;
        hnew[q] = f2bf(h);
      }
      u32* hbn = ((s + 1) & 1) ? hbB : hbA;
#pragma unroll
      for (int q = 0; q < 4; ++q) {
        const u32 nb = (u32)__shfl_xor((int)hnew[q], 1);
        if ((l & 1) == 0) {
          const u32 pk = (hnew[q] & 0xffffu) | (nb << 16);
          const int b = lh * 4 + q;
          const int c = ct * 16 + lr;
          *(u32*)(outp + (s * 128L + srow0 + b) * 896 + slab * 64 + c) = pk;
          ASTORE(hbn + b * 256 + (slab * 64 + c) / 2, pk);
        }
      }
    }
    // ---- per-group step barrier (round-2 proven form) ----
    asm volatile("s_waitcnt vmcnt(0)" ::: "memory");
    __syncthreads();
    if (tid == 0) {
      __hip_atomic_fetch_add(cnt, 1u, __ATOMIC_RELAXED, __HIP_MEMORY_SCOPE_AGENT);
      const u32 target = 8u * (u32)(s + 1);
      while (ALOAD(cnt) < target) __builtin_amdgcn_s_sleep(1);
    }
    __syncthreads();
  }
}

struct ScanAArgs {
  const float *w0ih, *w0hh, *b0ih, *b0hh;
  const float *w1ih, *w1hh, *b1ih, *b1hh;
  const float *w2ih, *w2hh, *b2ih, *b2hh;
  const u16 *xb, *xd2, *xd4;
  u16* hcat;
  u32 *hbuf0, *hbuf1, *cnt;
};

// gru0: 8 groups x 8 slabs (bid&7 -> XCD-local); gru1: 4 groups x 8 slabs;
// gru2: 8 single WGs. 104 WGs x 512 thr, 1 WG/CU (waves_per_eu(2,2)).
// waves_per_eu(2,2): cap occupancy -> 256-VGPR budget -> weights stay
// register-resident (the round-5 bottleneck).
__global__ void __launch_bounds__(512, 2)
__attribute__((amdgpu_waves_per_eu(2, 2)))
scanA(ScanAArgs a) {
  __shared__ __align__(16) char sm[33280];
  const int bid = blockIdx.x;
  if (bid < 64) {
    const int group = bid & 7, slab = bid >> 3;
    gru0_scan(a.w0ih, a.w0hh, a.b0ih, a.b0hh, a.xb, a.hcat, group, slab,
              a.hbuf0 + group * 4096, a.hbuf0 + 32768 + group * 4096,
              a.cnt + group * 16, sm);
  } else if (bid < 96) {
    const int id = bid - 64, group = id & 3, slab = id >> 2;
    gru_scan<256, 128, 32, 32, 8, 8>(a.w1ih, a.w1hh, a.b1ih, a.b1hh, a.xd2,
        a.hcat, 896, 512 + slab * 32, group, slab,
        a.hbuf1 + group * 4096, a.hbuf1 + 16384 + group * 4096,
        a.cnt + 128 + group * 16, sm);
  } else {
    const int g = bid - 96;
    gru_scan<128, 64, 16, 128, 8, 0>(a.w2ih, a.w2hh, a.b2ih, a.b2hh, a.xd4,
        a.hcat, 896, 768, g, 0, nullptr, nullptr, nullptr, sm);
  }
}

// block GRU scan: 8 WGs x 16 batch rows, whole H=128 per WG, input = LN(h)
__global__ void __launch_bounds__(512, 2)
__attribute__((amdgpu_waves_per_eu(2, 2)))
scanB(const float* __restrict__ wih,
    const float* __restrict__ whh, const float* __restrict__ bih,
    const float* __restrict__ bhh, const u16* __restrict__ ln, u16* __restrict__ y) {
  __shared__ __align__(16) char sm[8704];    // 16 rows x PITCH 544
  gru_scan<128, 128, 16, 128, 8, 0>(wih, whh, bih, bhh, ln, y, 128, 0,
                                    blockIdx.x, 0, nullptr, nullptr, nullptr, sm);
}

// x -> bf16 full / ::2 / ::4 copies, plus upsample-folded d0 weight
__global__ void __launch_bounds__(256) prep(const float* __restrict__ x,
    u16* __restrict__ xb, u16* __restrict__ xd2, u16* __restrict__ xd4,
    const float* __restrict__ d0w, u16* __restrict__ d0wf) {
  const int b = blockIdx.x;
  if (b < 16384) {
    const long t = b * 256L + threadIdx.x;       // 8-float chunk index
    const f4 aa = ((const f4*)x)[t * 2];
    const f4 cc = ((const f4*)x)[t * 2 + 1];
    const u16 u0 = f2bf(aa[0]), u1 = f2bf(aa[1]), u2 = f2bf(aa[2]), u3 = f2bf(aa[3]);
    const u16 u4 = f2bf(cc[0]), u5 = f2bf(cc[1]), u6 = f2bf(cc[2]), u7 = f2bf(cc[3]);
    short8 s8; s8[0]=(short)u0; s8[1]=(short)u1; s8[2]=(short)u2; s8[3]=(short)u3;
    s8[4]=(short)u4; s8[5]=(short)u5; s8[6]=(short)u6; s8[7]=(short)u7;
    *(short8*)(xb + t * 8) = s8;
    const long row = t >> 5; const int ch = (int)(t & 31);
    *(u32*)(xd2 + row * 128 + ch * 4)     = (u32)u0 | ((u32)u2 << 16);
    *(u32*)(xd2 + row * 128 + ch * 4 + 2) = (u32)u4 | ((u32)u6 << 16);
    *(u32*)(xd4 + row * 64 + ch * 2)      = (u32)u0 | ((u32)u4 << 16);
  } else {
    const int idx = (b - 16384) * 256 + threadIdx.x;   // 128*896
    const int o = idx / 896, c = idx % 896;
    float v;
    if (c < 512) v = d0w[o * 1536 + c];
    else if (c < 768) { const int j = c - 512; v = d0w[o * 1536 + 512 + 2 * j] + d0w[o * 1536 + 513 + 2 * j]; }
    else { const int j = c - 768; const float* p = d0w + o * 1536 + 1024 + 4 * j; v = p[0] + p[1] + p[2] + p[3]; }
    d0wf[idx] = f2bf(v);
  }
}

// d0 dense: (S*B,896)bf16 @ (128,896)bf16^T + bias, relu -> fp32
__global__ void __launch_bounds__(256) gemm_d0(const u16* __restrict__ A,
    const u16* __restrict__ Bw, const float* __restrict__ bias, float* __restrict__ C) {
  __shared__ __align__(16) u16 sA[128 * 40];   // pitch 40 elems breaks bank aliasing
  __shared__ __align__(16) u16 sB[128 * 40];
  const int tid = threadIdx.x, l = tid & 63, wv = tid >> 6;
  const int wm = wv >> 1, wn = wv & 1;
  const long m0 = (long)blockIdx.x * 128;
  f4 acc[4][4] = {};
  const int ra = tid & 127, half = tid >> 7;
  for (int kt = 0; kt < 28; ++kt) {
    const u16* gA = A + (m0 + ra) * 896 + kt * 32 + half * 16;
    const u16* gB = Bw + (long)ra * 896 + kt * 32 + half * 16;
    const short8 va0 = *(const short8*)(gA);
    const short8 va1 = *(const short8*)(gA + 8);
    const short8 vb0 = *(const short8*)(gB);
    const short8 vb1 = *(const short8*)(gB + 8);
    __syncthreads();
    *(short8*)(sA + ra * 40 + half * 16)     = va0;
    *(short8*)(sA + ra * 40 + half * 16 + 8) = va1;
    *(short8*)(sB + ra * 40 + half * 16)     = vb0;
    *(short8*)(sB + ra * 40 + half * 16 + 8) = vb1;
    __syncthreads();
    short8 af[4], bfv[4];
#pragma unroll
    for (int i = 0; i < 4; ++i) {
      af[i]  = *(const short8*)(sA + (wm * 64 + i * 16 + (l & 15)) * 40 + (l >> 4) * 8);
      bfv[i] = *(const short8*)(sB + (wn * 64 + i * 16 + (l & 15)) * 40 + (l >> 4) * 8);
    }
#pragma unroll
    for (int i = 0; i < 4; ++i)
#pragma unroll
      for (int j = 0; j < 4; ++j)
        acc[i][j] = MFMA16(af[i], bfv[j], acc[i][j], 0, 0, 0);
  }
#pragma unroll
  for (int i = 0; i < 4; ++i) {
    const int m = wm * 64 + i * 16 + (l >> 4) * 4;
#pragma unroll
    for (int j = 0; j < 4; ++j) {
      const int n = wn * 64 + j * 16 + (l & 15);
      const float bs = bias[n];
#pragma unroll
      for (int q = 0; q < 4; ++q) {
        const float v = acc[i][j][q] + bs;
        C[(m0 + m + q) * 128 + n] = v > 0.f ? v : 0.f;
      }
    }
  }
}

// LayerNorm over 128; RESID: h1 = h0 + y (write fp32) then LN(h1)
template<bool RESID>
__global__ void __launch_bounds__(256) ln_k(const float* __restrict__ hin,
    const u16* __restrict__ yin, const float* __restrict__ g, const float* __restrict__ b,
    u16* __restrict__ lnout, float* __restrict__ hout) {
  const long row = blockIdx.x * 4L + (threadIdx.x >> 6);
  const int l = threadIdx.x & 63;
  float vx = hin[row * 128 + l * 2], vy = hin[row * 128 + l * 2 + 1];
  if constexpr (RESID) {
    const u32 yp = *(const u32*)(yin + row * 128 + l * 2);
    vx += bf2f(yp & 0xffffu); vy += bf2f(yp >> 16);
    float2 w = {vx, vy};
    *(float2*)(hout + row * 128 + l * 2) = w;
  }
  float s1 = vx + vy, s2 = vx * vx + vy * vy;
#pragma unroll
  for (int o = 1; o < 64; o <<= 1) { s1 += __shfl_xor(s1, o); s2 += __shfl_xor(s2, o); }
  const float m = s1 * 0.0078125f;
  const float rs = rsqrtf(s2 * 0.0078125f - m * m + 1e-5f);
  const float o0 = (vx - m) * rs * g[l * 2] + b[l * 2];
  const float o1 = (vy - m) * rs * g[l * 2 + 1] + b[l * 2 + 1];
  *(u32*)(lnout + row * 128 + l * 2) = (u32)f2bf(o0) | ((u32)f2bf(o1) << 16);
}

// out = (h1 + y) @ df_w^T + df_b  (full fp32)
__global__ void __launch_bounds__(256) final_k(const float* __restrict__ h1,
    const u16* __restrict__ y, const float* __restrict__ w, const float* __restrict__ wb,
    float* __restrict__ out) {
  __shared__ float sw[512];
  __shared__ float sb[4];
  if (threadIdx.x < 4) sb[threadIdx.x] = wb[threadIdx.x];
  for (int i = threadIdx.x; i < 512; i += 256) sw[i] = w[i];
  __syncthreads();
  const long row = blockIdx.x * 256L + threadIdx.x;
  float a0 = sb[0], a1 = sb[1], a2 = sb[2], a3 = sb[3];
  const float* hr = h1 + row * 128;
  const u16* yr = y + row * 128;
#pragma unroll 4
  for (int c = 0; c < 128; c += 4) {
    const f4 hv = *(const f4*)(hr + c);
    const u32 y0 = *(const u32*)(yr + c);
    const u32 y1 = *(const u32*)(yr + c + 2);
    const float v0 = hv[0] + bf2f(y0 & 0xffffu);
    const float v1 = hv[1] + bf2f(y0 >> 16);
    const float v2 = hv[2] + bf2f(y1 & 0xffffu);
    const float v3 = hv[3] + bf2f(y1 >> 16);
    a0 += v0 * sw[c]       + v1 * sw[c + 1]       + v2 * sw[c + 2]       + v3 * sw[c + 3];
    a1 += v0 * sw[128 + c] + v1 * sw[128 + c + 1] + v2 * sw[128 + c + 2] + v3 * sw[128 + c + 3];
    a2 += v0 * sw[256 + c] + v1 * sw[256 + c + 1] + v2 * sw[256 + c + 2] + v3 * sw[256 + c + 3];
    a3 += v0 * sw[384 + c] + v1 * sw[384 + c + 1] + v2 * sw[384 + c + 2] + v3 * sw[384 + c + 3];
  }
  f4 o = {a0, a1, a2, a3};
  *(f4*)(out + row * 4) = o;
}

extern "C" void kernel_launch(void* const* d_in, const int* in_sizes, int n_in,
                              void* d_out, int out_size, void* d_ws, size_t ws_size,
                              hipStream_t stream) {
  char* ws = (char*)d_ws;
  const float* x     = (const float*)d_in[0];
  const float* g0wih = (const float*)d_in[1];
  const float* g0whh = (const float*)d_in[2];
  const float* g0bih = (const float*)d_in[3];
  const float* g0bhh = (const float*)d_in[4];
  const float* g1wih = (const float*)d_in[5];
  const float* g1whh = (const float*)d_in[6];
  const float* g1bih = (const float*)d_in[7];
  const float* g1bhh = (const float*)d_in[8];
  const float* g2wih = (const float*)d_in[9];
  const float* g2whh = (const float*)d_in[10];
  const float* g2bih = (const float*)d_in[11];
  const float* g2bhh = (const float*)d_in[12];
  const float* d0w   = (const float*)d_in[13];
  const float* d0b   = (const float*)d_in[14];
  const float* ln0g  = (const float*)d_in[15];
  const float* ln0b  = (const float*)d_in[16];
  const float* b0wih = (const float*)d_in[17];
  const float* b0whh = (const float*)d_in[18];
  const float* b0bih = (const float*)d_in[19];
  const float* b0bhh = (const float*)d_in[20];
  const float* ln1g  = (const float*)d_in[21];
  const float* ln1b  = (const float*)d_in[22];
  const float* b1wih = (const float*)d_in[23];
  const float* b1whh = (const float*)d_in[24];
  const float* b1bih = (const float*)d_in[25];
  const float* b1bhh = (const float*)d_in[26];
  const float* dfw   = (const float*)d_in[27];
  const float* dfb   = (const float*)d_in[28];

  u16* xb    = (u16*)(ws + OFF_XB);
  u16* xd2   = (u16*)(ws + OFF_XD2);
  u16* xd4   = (u16*)(ws + OFF_XD4);
  u16* hcat  = (u16*)(ws + OFF_HCAT);
  u16* y     = (u16*)(ws + OFF_Y);
  float* h1f = (float*)(ws + OFF_H1);
  u16* d0wf  = (u16*)(ws + OFF_D0WF);
  u32* hbuf0 = (u32*)(ws + OFF_HB0);
  u32* hbuf1 = (u32*)(ws + OFF_HB1);
  u32* cnt   = (u32*)(ws + OFF_CNT);
  // phase aliases (x buffers are dead after scanA)
  float* h0f = (float*)(ws + OFF_XB);
  u16* lnbuf = (u16*)(ws + OFF_XD2);

  // reset h broadcast buffers + barrier counters (h0 = 0, counters = 0)
  hipMemsetAsync(ws + OFF_HB0, 0, (size_t)(OFF_CNT + 1024 - OFF_HB0), stream);

  prep<<<16832, 256, 0, stream>>>(x, xb, xd2, xd4, d0w, d0wf);

  ScanAArgs sa;
  sa.w0ih = g0wih; sa.w0hh = g0whh; sa.b0ih = g0bih; sa.b0hh = g0bhh;
  sa.w1ih = g1wih; sa.w1hh = g1whh; sa.b1ih = g1bih; sa.b1hh = g1bhh;
  sa.w2ih = g2wih; sa.w2hh = g2whh; sa.b2ih = g2bih; sa.b2hh = g2bhh;
  sa.xb = xb; sa.xd2 = xd2; sa.xd4 = xd4;
  sa.hcat = hcat; sa.hbuf0 = hbuf0; sa.hbuf1 = hbuf1; sa.cnt = cnt;
  scanA<<<104, 512, 0, stream>>>(sa);

  gemm_d0<<<1024, 256, 0, stream>>>(hcat, d0wf, d0b, h0f);

  ln_k<false><<<32768, 256, 0, stream>>>(h0f, nullptr, ln0g, ln0b, lnbuf, nullptr);
  scanB<<<8, 512, 0, stream>>>(b0wih, b0whh, b0bih, b0bhh, lnbuf, y);
  ln_k<true><<<32768, 256, 0, stream>>>(h0f, y, ln1g, ln1b, lnbuf, h1f);
  scanB<<<8, 512, 0, stream>>>(b1wih, b1whh, b1bih, b1bhh, lnbuf, y);

  final_k<<<512, 256, 0, stream>>>(h1f, y, dfw, dfb, (float*)d_out);
}

// Round 7
// 6867.014 us; speedup vs baseline: 1.1050x; 1.1050x over previous
//
#include <hip/hip_runtime.h>

typedef unsigned int u32;
typedef unsigned short u16;
typedef __attribute__((ext_vector_type(8))) short short8;
typedef __attribute__((ext_vector_type(4))) float f4;

#define MFMA16 __builtin_amdgcn_mfma_f32_16x16x32_bf16
#define ALOAD(p)    __hip_atomic_load((p), __ATOMIC_RELAXED, __HIP_MEMORY_SCOPE_AGENT)
#define ASTORE(p,v) __hip_atomic_store((p), (v), __ATOMIC_RELAXED, __HIP_MEMORY_SCOPE_AGENT)

// ---------- workspace layout (bytes) ----------
#define OFF_XB    0LL            // x bf16 (67,108,864)  [aliased: h0f fp32 after scans]
#define OFF_XD2   67108864LL     // x[::2] bf16 (33,554,432) [aliased: lnbuf]
#define OFF_XD4   100663296LL    // x[::4] bf16 (16,777,216)
#define OFF_HCAT  117440512LL    // concat bf16 (234,881,024)
#define OFF_Y     352321536LL    // y0 bf16 (33,554,432)
#define OFF_H1    385875968LL    // y1 bf16 (33,554,432; region is 64MB)
#define OFF_D0WF  452984832LL    // folded d0 weight bf16 (229,376)
#define OFF_HB0   453214208LL    // gru0 h bcast: 2 par x 8 g x 16x512 bf16 = 262,144
#define OFF_HB1   453476352LL    // gru1 h bcast: 2 par x 4 g x 32x256 bf16 = 131,072
#define OFF_FLG   453607424LL    // flag region (16,384; stride-16-u32 flags)
#define WS_TOTAL  453623808LL

__device__ __forceinline__ u16 f2bf(float f) {
  u32 u = __float_as_uint(f);
  return (u16)((u + 0x7fffu + ((u >> 16) & 1u)) >> 16);   // RNE
}
__device__ __forceinline__ float bf2f(u32 b) { return __uint_as_float(b << 16); }
__device__ __forceinline__ float sigm(float x) { return __builtin_amdgcn_rcpf(1.f + __expf(-x)); }
__device__ __forceinline__ float tanh_(float x) { return 1.f - 2.f * __builtin_amdgcn_rcpf(1.f + __expf(2.f * x)); }

__device__ __forceinline__ short8 cvt8(const float* p) {
  short8 r;
#pragma unroll
  for (int j = 0; j < 8; ++j) r[j] = (short)f2bf(p[j]);
  return r;
}

// =====================================================================
// Generic fused GRU scan. Wave-role branches SCALARIZED (readfirstlane) —
// MFMA ignores EXEC; if-converted role branches corrupt accumulators.
// GROUP_WGS > 0: column-split group; per-WG FLAG handshake:
//   end of step s: publish h (agent ASTORE) -> vmcnt(0) -> sync ->
//   flag[me]=s+1 -> output stores (off critical path).
//   top of step s: wave0 polls all flags >= s (one vector load), sync.
// PUB=1 (GROUP_WGS==0): producer mode — output stores are agent ASTOREs,
//   then vmcnt(0)/sync/flag=s+1 (consumed by gruB1).
// =====================================================================
template<int KH, int KX, int BT, int CSPAN, int WAVES, int GROUP_WGS, int PUB>
__device__ __forceinline__ void gru_scan(
    const float* __restrict__ wih, const float* __restrict__ whh,
    const float* __restrict__ bih, const float* __restrict__ bhh,
    const u16* __restrict__ xsrc,                     // [S*128][KX] bf16
    u16* __restrict__ outp, const int outPitch, const int outColBase,
    const int group, const int slab,
    u32* __restrict__ hbA, u32* __restrict__ hbB, u32* __restrict__ flags,
    char* sm)
{
  constexpr int H = KH;
  constexpr int KT = (KH + KX) / 32;
  constexpr int KH32 = KH / 32;
  constexpr int PITCH = (KH + KX) * 2 + 32;
  constexpr int CT_N = CSPAN / 16;
  constexpr int NTILES = (BT / 16) * CT_N;
  constexpr int MAXP = (NTILES + WAVES - 1) / WAVES;
  constexpr int NT = WAVES * 64;
  constexpr int NX = (BT * KX / 2) / NT;
  constexpr int NH = (BT * KH / 2) / NT;
  constexpr bool GH = (GROUP_WGS > 0);

  const int tid = threadIdx.x;
  const int l = tid & 63;
  const int wv = __builtin_amdgcn_readfirstlane(tid >> 6);  // SCALAR wave id
  const int lr = l & 15;
  const int lh = l >> 4;
  const long srow0 = group * BT;

  // ---- weight B-fragments in registers (once) ----
  short8 Br[MAXP][KT], Bz[MAXP][KT], Bn[MAXP][KT];
  float bb0[MAXP], bb1[MAXP], bb2[MAXP], bb3[MAXP];
  float hk[MAXP][4];
#pragma unroll
  for (int p = 0; p < MAXP; ++p) {
    const int tp = wv + WAVES * p;
    const int tpc = (tp < NTILES) ? tp : 0;
    const int ct = tpc % CT_N;
    const int gcol = slab * CSPAN + ct * 16 + lr;
#pragma unroll
    for (int t = 0; t < KT; ++t) {
      const int k = t * 32 + lh * 8;
      if (t < KH32) {
        Br[p][t] = cvt8(whh + (long)(0 * H + gcol) * KH + k);
        Bz[p][t] = cvt8(whh + (long)(1 * H + gcol) * KH + k);
        Bn[p][t] = cvt8(whh + (long)(2 * H + gcol) * KH + k);
      } else {
        const int kx = k - KH;
        Br[p][t] = cvt8(wih + (long)(0 * H + gcol) * KX + kx);
        Bz[p][t] = cvt8(wih + (long)(1 * H + gcol) * KX + kx);
        Bn[p][t] = cvt8(wih + (long)(2 * H + gcol) * KX + kx);
      }
    }
    bb0[p] = bih[0 * H + gcol] + bhh[0 * H + gcol];
    bb1[p] = bih[1 * H + gcol] + bhh[1 * H + gcol];
    bb2[p] = bih[2 * H + gcol];
    bb3[p] = bhh[2 * H + gcol];
    hk[p][0] = hk[p][1] = hk[p][2] = hk[p][3] = 0.f;
  }

  if constexpr (!GH) {           // zero local h (h0 = 0)
#pragma unroll
    for (int i = 0; i < (BT * KH / 2 + NT - 1) / NT; ++i) {
      const int idx = tid + NT * i;
      if (idx < BT * KH / 2) {
        const int r = idx / (KH / 2), d = idx % (KH / 2);
        *(u32*)(sm + r * PITCH + ((d * 4) ^ ((r & 7) << 4))) = 0u;
      }
    }
  }

  u32 xr[NX];                    // x prefetch for step 0
#pragma unroll
  for (int i = 0; i < NX; ++i) {
    const int idx = tid + NT * i;
    const int r = idx / (KX / 2), d = idx % (KX / 2);
    xr[i] = *(const u32*)(xsrc + (srow0 + r) * KX + d * 2);
  }

  for (int s = 0; s < 1024; ++s) {
    // ---- top wait: peers published h_s (flag >= s); h_0 pre-zeroed ----
    if constexpr (GH) {
      if (wv == 0) {
        const u32 tgt = (u32)s;
        for (;;) {
          const u32 f = (l < GROUP_WGS) ? ALOAD(flags + l * 16) : tgt;
          if (__all(f >= tgt)) break;
        }
      }
      __syncthreads();
    }
    // ---- stage x ----
#pragma unroll
    for (int i = 0; i < NX; ++i) {
      const int idx = tid + NT * i;
      const int r = idx / (KX / 2), d = idx % (KX / 2);
      *(u32*)(sm + r * PITCH + ((KH * 2 + d * 4) ^ ((r & 7) << 4))) = xr[i];
    }
    // ---- stage h (coherent loads) ----
    if constexpr (GH) {
      const u32* hb = (s & 1) ? hbB : hbA;
#pragma unroll
      for (int i = 0; i < NH; ++i) {
        const int idx = tid + NT * i;
        const int r = idx / (KH / 2), d = idx % (KH / 2);
        const u32 v = ALOAD(hb + r * (KH / 2) + d);
        *(u32*)(sm + r * PITCH + ((d * 4) ^ ((r & 7) << 4))) = v;
      }
    }
    // ---- prefetch next x (deep slack; done before handshake drain) ----
    if (s + 1 < 1024) {
#pragma unroll
      for (int i = 0; i < NX; ++i) {
        const int idx = tid + NT * i;
        const int r = idx / (KX / 2), d = idx % (KX / 2);
        xr[i] = *(const u32*)(xsrc + ((s + 1) * 128L + srow0 + r) * KX + d * 2);
      }
    }
    __syncthreads();

    // ---- per-wave gate-triple MFMA (scalar role branch) ----
    u32 hnew[MAXP][4];
#pragma unroll
    for (int p = 0; p < MAXP; ++p) {
      const int tp = wv + WAVES * p;
      if (tp < NTILES) {
        const int mt = tp / CT_N;
        f4 ar = {0.f, 0.f, 0.f, 0.f}; f4 az = ar, anh = ar, anx = ar;
#pragma unroll
        for (int t = 0; t < KT; ++t) {
          const int row = mt * 16 + lr;
          const short8 a = *(const short8*)(sm + row * PITCH +
                              ((t * 64 + lh * 16) ^ ((row & 7) << 4)));
          ar = MFMA16(a, Br[p][t], ar, 0, 0, 0);
          az = MFMA16(a, Bz[p][t], az, 0, 0, 0);
          if (t < KH32) anh = MFMA16(a, Bn[p][t], anh, 0, 0, 0);
          else          anx = MFMA16(a, Bn[p][t], anx, 0, 0, 0);
        }
#pragma unroll
        for (int q = 0; q < 4; ++q) {
          const float rg = sigm(ar[q] + bb0[p]);
          const float zg = sigm(az[q] + bb1[p]);
          const float ng = tanh_(anx[q] + bb2[p] + rg * (anh[q] + bb3[p]));
          const float h = (1.f - zg) * ng + zg * hk[p][q];
          hk[p][q] = h;
          hnew[p][q] = f2bf(h);
        }
      }
    }
    if constexpr (!GH) __syncthreads();   // A-tile reads done before h rewrite

    // ---- write phase ----
    u32 pk[MAXP][4];
#pragma unroll
    for (int p = 0; p < MAXP; ++p) {
      const int tp = wv + WAVES * p;
      if (tp < NTILES) {
        const int mt = tp / CT_N, ct = tp % CT_N;
        const int c = ct * 16 + lr;
#pragma unroll
        for (int q = 0; q < 4; ++q) {
          const u32 nb = (u32)__shfl_xor((int)hnew[p][q], 1);
          pk[p][q] = (hnew[p][q] & 0xffffu) | (nb << 16);
          if ((l & 1) == 0) {
            const int b = mt * 16 + lh * 4 + q;
            if constexpr (GH) {            // publish only (output after flag)
              u32* hbn = ((s + 1) & 1) ? hbB : hbA;
              ASTORE(hbn + b * (KH / 2) + (slab * CSPAN + c) / 2, pk[p][q]);
            } else {
              u32* oa = (u32*)(outp + (s * 128L + srow0 + b) * outPitch + outColBase + c);
              if constexpr (PUB) ASTORE(oa, pk[p][q]); else *oa = pk[p][q];
              *(u32*)(sm + b * PITCH + ((c * 2) ^ ((b & 7) << 4))) = pk[p][q];
            }
          }
        }
      }
    }
    // ---- handshake ----
    if constexpr (GH) {
      asm volatile("s_waitcnt vmcnt(0)" ::: "memory");  // publishes ack'd
      __syncthreads();
      if (tid == 0) ASTORE(flags + slab * 16, (u32)(s + 1));
      // output stores off the critical path
#pragma unroll
      for (int p = 0; p < MAXP; ++p) {
        const int tp = wv + WAVES * p;
        if (tp < NTILES) {
          const int mt = tp / CT_N, ct = tp % CT_N;
          const int c = ct * 16 + lr;
#pragma unroll
          for (int q = 0; q < 4; ++q) {
            if ((l & 1) == 0) {
              const int b = mt * 16 + lh * 4 + q;
              *(u32*)(outp + (s * 128L + srow0 + b) * outPitch + outColBase + c) = pk[p][q];
            }
          }
        }
      }
    } else if constexpr (PUB) {
      asm volatile("s_waitcnt vmcnt(0)" ::: "memory");
      __syncthreads();
      if (tid == 0) ASTORE(flags, (u32)(s + 1));
    }
  }
}

// =====================================================================
// gru0 (H=512, Kin=256): GATE-SPLIT scan (r5-proven math) + flag handshake.
//   gg0 (waves 0-3): r (24t) + n h-part (16t), gates + publish + stores;
//   gg1 (waves 4-7): z (24t) + n x-part (8t), export via LDS reduce.
// =====================================================================
__device__ __forceinline__ void gru0_scan(
    const float* __restrict__ wih, const float* __restrict__ whh,
    const float* __restrict__ bih, const float* __restrict__ bhh,
    const u16* __restrict__ x, u16* __restrict__ outp,
    const int group, const int slab,
    u32* __restrict__ hbA, u32* __restrict__ hbB, u32* __restrict__ flags,
    char* sm)
{
  constexpr int PITCH = 1568;
  const int tid = threadIdx.x;
  const int l = tid & 63;
  const int wv = __builtin_amdgcn_readfirstlane(tid >> 6);  // SCALAR
  const int lr = l & 15, lh = l >> 4;
  const int ct = wv & 3, gg = wv >> 2;
  const long srow0 = group * 16;
  const int gcol = slab * 64 + ct * 16 + lr;
  f4* red = (f4*)(sm + 25088);

  short8 W0[24], W1[16];
#pragma unroll
  for (int t = 0; t < 24; ++t) {
    const int k = t * 32 + lh * 8;
    if (t < 16) W0[t] = cvt8(whh + (long)(gg * 512 + gcol) * 512 + k);
    else        W0[t] = cvt8(wih + (long)(gg * 512 + gcol) * 256 + (k - 512));
  }
  if (gg == 0) {
#pragma unroll
    for (int t = 0; t < 16; ++t)
      W1[t] = cvt8(whh + (long)(2 * 512 + gcol) * 512 + t * 32 + lh * 8);
  } else {
#pragma unroll
    for (int t = 0; t < 8; ++t)
      W1[t] = cvt8(wih + (long)(2 * 512 + gcol) * 256 + t * 32 + lh * 8);
  }
  const float bb0 = bih[0 * 512 + gcol] + bhh[0 * 512 + gcol];
  const float bb1 = bih[1 * 512 + gcol] + bhh[1 * 512 + gcol];
  const float bb2 = bih[2 * 512 + gcol];
  const float bb3 = bhh[2 * 512 + gcol];
  float hk[4] = {0.f, 0.f, 0.f, 0.f};

  u32 xr[4];
#pragma unroll
  for (int i = 0; i < 4; ++i) {
    const int idx = tid + 512 * i;
    const int r = idx >> 7, d = idx & 127;
    xr[i] = *(const u32*)(x + (srow0 + r) * 256 + d * 2);
  }

  for (int s = 0; s < 1024; ++s) {
    // top wait: all 8 slabs published h_s
    if (wv == 0) {
      const u32 tgt = (u32)s;
      for (;;) {
        const u32 f = (l < 8) ? ALOAD(flags + l * 16) : tgt;
        if (__all(f >= tgt)) break;
      }
    }
    __syncthreads();
    // stage x
#pragma unroll
    for (int i = 0; i < 4; ++i) {
      const int idx = tid + 512 * i;
      const int r = idx >> 7, d = idx & 127;
      *(u32*)(sm + r * PITCH + ((1024 + d * 4) ^ ((r & 7) << 4))) = xr[i];
    }
    // stage h
    {
      const u32* hb = (s & 1) ? hbB : hbA;
#pragma unroll
      for (int i = 0; i < 8; ++i) {
        const int idx = tid + 512 * i;
        const int r = idx >> 8, d = idx & 255;
        const u32 v = ALOAD(hb + r * 256 + d);
        *(u32*)(sm + r * PITCH + ((d * 4) ^ ((r & 7) << 4))) = v;
      }
    }
    if (s + 1 < 1024) {
#pragma unroll
      for (int i = 0; i < 4; ++i) {
        const int idx = tid + 512 * i;
        const int r = idx >> 7, d = idx & 127;
        xr[i] = *(const u32*)(x + ((s + 1) * 128L + srow0 + r) * 256 + d * 2);
      }
    }
    __syncthreads();

    f4 a0 = {0.f, 0.f, 0.f, 0.f}, a1 = a0;
    if (gg == 0) {
#pragma unroll
      for (int t = 0; t < 24; ++t) {
        const short8 a = *(const short8*)(sm + lr * PITCH +
                            ((t * 64 + lh * 16) ^ ((lr & 7) << 4)));
        a0 = MFMA16(a, W0[t], a0, 0, 0, 0);
        if (t < 16) a1 = MFMA16(a, W1[t], a1, 0, 0, 0);
      }
    } else {
#pragma unroll
      for (int t = 0; t < 24; ++t) {
        const short8 a = *(const short8*)(sm + lr * PITCH +
                            ((t * 64 + lh * 16) ^ ((lr & 7) << 4)));
        a0 = MFMA16(a, W0[t], a0, 0, 0, 0);
        if (t >= 16) a1 = MFMA16(a, W1[t - 16], a1, 0, 0, 0);
      }
      red[(ct * 2 + 0) * 64 + l] = a0;        // az
      red[(ct * 2 + 1) * 64 + l] = a1;        // anx
    }
    __syncthreads();
    u32 pk[4];
    if (gg == 0) {
      const f4 paz  = red[(ct * 2 + 0) * 64 + l];
      const f4 panx = red[(ct * 2 + 1) * 64 + l];
      u32 hnew[4];
#pragma unroll
      for (int q = 0; q < 4; ++q) {
        const float rg = sigm(a0[q] + bb0);
        const float zg = sigm(paz[q] + bb1);
        const float ng = tanh_(panx[q] + bb2 + rg * (a1[q] + bb3));
        const float h = (1.f - zg) * ng + zg * hk[q];
        hk[q] = h;
        hnew[q] = f2bf(h);
      }
      u32* hbn = ((s + 1) & 1) ? hbB : hbA;
#pragma unroll
      for (int q = 0; q < 4; ++q) {
        const u32 nb = (u32)__shfl_xor((int)hnew[q], 1);
        pk[q] = (hnew[q] & 0xffffu) | (nb << 16);
        if ((l & 1) == 0) {
          const int b = lh * 4 + q;
          const int c = ct * 16 + lr;
          ASTORE(hbn + b * 256 + (slab * 64 + c) / 2, pk[q]);   // publish only
        }
      }
    }
    asm volatile("s_waitcnt vmcnt(0)" ::: "memory");   // publishes ack'd
    __syncthreads();
    if (tid == 0) ASTORE(flags + slab * 16, (u32)(s + 1));
    if (gg == 0) {                                     // hcat off critical path
#pragma unroll
      for (int q = 0; q < 4; ++q) {
        if ((l & 1) == 0) {
          const int b = lh * 4 + q;
          const int c = ct * 16 + lr;
          *(u32*)(outp + (s * 128L + srow0 + b) * 896 + slab * 64 + c) = pk[q];
        }
      }
    }
  }
}

// =====================================================================
// Block-GRU consumer (b1): waits y0[s] from paired producer, computes
// h1 = h0 + y0, LN1 inline, then its GRU step (all-local h). Writes y1.
// =====================================================================
__device__ __forceinline__ void gruB1_scan(
    const float* __restrict__ wih, const float* __restrict__ whh,
    const float* __restrict__ bih, const float* __restrict__ bhh,
    const float* __restrict__ h0f, const u16* __restrict__ y0,
    const float* __restrict__ lng, const float* __restrict__ lnb,
    u16* __restrict__ y1, u32* __restrict__ flag, const int grp, char* sm)
{
  constexpr int PITCH = 544;               // (128+128)*2 + 32
  const int tid = threadIdx.x;
  const int l = tid & 63;
  const int wv = __builtin_amdgcn_readfirstlane(tid >> 6);  // = col-tile
  const int lr = l & 15, lh = l >> 4;
  const int gcol = wv * 16 + lr;

  short8 Br[8], Bz[8], Bn[8];
#pragma unroll
  for (int t = 0; t < 8; ++t) {
    const int k = t * 32 + lh * 8;
    if (t < 4) {
      Br[t] = cvt8(whh + (long)(0 * 128 + gcol) * 128 + k);
      Bz[t] = cvt8(whh + (long)(1 * 128 + gcol) * 128 + k);
      Bn[t] = cvt8(whh + (long)(2 * 128 + gcol) * 128 + k);
    } else {
      const int kx = k - 128;
      Br[t] = cvt8(wih + (long)(0 * 128 + gcol) * 128 + kx);
      Bz[t] = cvt8(wih + (long)(1 * 128 + gcol) * 128 + kx);
      Bn[t] = cvt8(wih + (long)(2 * 128 + gcol) * 128 + kx);
    }
  }
  const float bb0 = bih[0 * 128 + gcol] + bhh[0 * 128 + gcol];
  const float bb1 = bih[1 * 128 + gcol] + bhh[1 * 128 + gcol];
  const float bb2 = bih[2 * 128 + gcol];
  const float bb3 = bhh[2 * 128 + gcol];
  float hk[4] = {0.f, 0.f, 0.f, 0.f};

  // zero local h region (16 rows x 64 dwords)
#pragma unroll
  for (int i = 0; i < 2; ++i) {
    const int idx = tid + 512 * i;
    const int r = idx >> 6, d = idx & 63;
    *(u32*)(sm + r * PITCH + ((d * 4) ^ ((r & 7) << 4))) = 0u;
  }

  // LN thread mapping: row rr (16), quad c4
  const int rr = tid >> 5;
  const int c4 = (tid & 31) * 4;
  const float gw0 = lng[c4], gw1 = lng[c4 + 1], gw2 = lng[c4 + 2], gw3 = lng[c4 + 3];
  const float bw0 = lnb[c4], bw1 = lnb[c4 + 1], bw2 = lnb[c4 + 2], bw3 = lnb[c4 + 3];
  f4 hv = *(const f4*)(h0f + (long)(grp * 16 + rr) * 128 + c4);   // h0[0] prefetch

  for (int s = 0; s < 1024; ++s) {
    if (wv == 0) { while (ALOAD(flag) < (u32)(s + 1)) {} }
    __syncthreads();
    const long row = (long)s * 128 + grp * 16 + rr;
    const u32 ya = ALOAD((const u32*)y0 + row * 64 + (tid & 31) * 2);
    const u32 yb = ALOAD((const u32*)y0 + row * 64 + (tid & 31) * 2 + 1);
    const float v0 = hv[0] + bf2f(ya & 0xffffu);
    const float v1 = hv[1] + bf2f(ya >> 16);
    const float v2 = hv[2] + bf2f(yb & 0xffffu);
    const float v3 = hv[3] + bf2f(yb >> 16);
    if (s + 1 < 1024)
      hv = *(const f4*)(h0f + (row + 128) * 128 + c4);   // prefetch h0[s+1]
    float s1 = v0 + v1 + v2 + v3;
    float s2 = v0 * v0 + v1 * v1 + v2 * v2 + v3 * v3;
#pragma unroll
    for (int o = 1; o < 32; o <<= 1) { s1 += __shfl_xor(s1, o); s2 += __shfl_xor(s2, o); }
    const float m = s1 * 0.0078125f;
    const float rs = rsqrtf(s2 * 0.0078125f - m * m + 1e-5f);
    const u32 p0 = (u32)f2bf((v0 - m) * rs * gw0 + bw0) |
                   ((u32)f2bf((v1 - m) * rs * gw1 + bw1) << 16);
    const u32 p1 = (u32)f2bf((v2 - m) * rs * gw2 + bw2) |
                   ((u32)f2bf((v3 - m) * rs * gw3 + bw3) << 16);
    const int d0 = (tid & 31) * 2;
    char* xa = sm + rr * PITCH + ((256 + d0 * 4) ^ ((rr & 7) << 4));
    *(u32*)xa = p0;
    *(u32*)(xa + 4) = p1;
    __syncthreads();

    f4 ar = {0.f, 0.f, 0.f, 0.f}; f4 az = ar, anh = ar, anx = ar;
#pragma unroll
    for (int t = 0; t < 8; ++t) {
      const short8 a = *(const short8*)(sm + lr * PITCH +
                          ((t * 64 + lh * 16) ^ ((lr & 7) << 4)));
      ar = MFMA16(a, Br[t], ar, 0, 0, 0);
      az = MFMA16(a, Bz[t], az, 0, 0, 0);
      if (t < 4) anh = MFMA16(a, Bn[t], anh, 0, 0, 0);
      else       anx = MFMA16(a, Bn[t], anx, 0, 0, 0);
    }
    u32 hnew[4];
#pragma unroll
    for (int q = 0; q < 4; ++q) {
      const float rg = sigm(ar[q] + bb0);
      const float zg = sigm(az[q] + bb1);
      const float ng = tanh_(anx[q] + bb2 + rg * (anh[q] + bb3));
      const float h = (1.f - zg) * ng + zg * hk[q];
      hk[q] = h;
      hnew[q] = f2bf(h);
    }
    __syncthreads();                        // A-tile reads done before h rewrite
#pragma unroll
    for (int q = 0; q < 4; ++q) {
      const u32 nb = (u32)__shfl_xor((int)hnew[q], 1);
      if ((l & 1) == 0) {
        const u32 pk = (hnew[q] & 0xffffu) | (nb << 16);
        const int b = lh * 4 + q;
        const int c = wv * 16 + lr;
        *(u32*)(y1 + ((long)s * 128 + grp * 16 + b) * 128 + c) = pk;
        *(u32*)(sm + b * PITCH + ((c * 2) ^ ((b & 7) << 4))) = pk;
      }
    }
  }
}

struct ScanAArgs {
  const float *w0ih, *w0hh, *b0ih, *b0hh;
  const float *w1ih, *w1hh, *b1ih, *b1hh;
  const float *w2ih, *w2hh, *b2ih, *b2hh;
  const u16 *xb, *xd2, *xd4;
  u16* hcat;
  u32 *hbuf0, *hbuf1, *flg;
};

// gru0: 8 groups x 8 slabs (bid&7 -> XCD-local); gru1: 4 groups x 8 slabs;
// gru2: 8 single WGs. 104 WGs x 512 thr.
__global__ void __launch_bounds__(512, 2) scanA(ScanAArgs a) {
  __shared__ __align__(16) char sm[33280];
  const int bid = blockIdx.x;
  if (bid < 64) {
    const int group = bid & 7, slab = bid >> 3;
    gru0_scan(a.w0ih, a.w0hh, a.b0ih, a.b0hh, a.xb, a.hcat, group, slab,
              a.hbuf0 + group * 4096, a.hbuf0 + 32768 + group * 4096,
              a.flg + group * 128, sm);
  } else if (bid < 96) {
    const int id = bid - 64, group = id & 3, slab = id >> 2;
    gru_scan<256, 128, 32, 32, 8, 8, 0>(a.w1ih, a.w1hh, a.b1ih, a.b1hh, a.xd2,
        a.hcat, 896, 512 + slab * 32, group, slab,
        a.hbuf1 + group * 4096, a.hbuf1 + 16384 + group * 4096,
        a.flg + 1024 + group * 128, sm);
  } else {
    const int g = bid - 96;
    gru_scan<128, 64, 16, 128, 8, 0, 0>(a.w2ih, a.w2hh, a.b2ih, a.b2hh, a.xd4,
        a.hcat, 896, 768, g, 0, nullptr, nullptr, nullptr, sm);
  }
}

// Fused block-GRU pair: bid<8 -> b0 producer (LN0 input precomputed);
// bid>=8 -> b1 consumer with inline LN1, 1-step lag via flag.
__global__ void __launch_bounds__(512, 2) scanB2(
    const float* __restrict__ b0wih, const float* __restrict__ b0whh,
    const float* __restrict__ b0bih, const float* __restrict__ b0bhh,
    const float* __restrict__ b1wih, const float* __restrict__ b1whh,
    const float* __restrict__ b1bih, const float* __restrict__ b1bhh,
    const u16* __restrict__ lnbuf, const float* __restrict__ h0f,
    const float* __restrict__ ln1g, const float* __restrict__ ln1b,
    u16* __restrict__ y0, u16* __restrict__ y1, u32* __restrict__ flg) {
  __shared__ __align__(16) char sm[8704];
  const int bid = blockIdx.x;
  if (bid < 8) {
    gru_scan<128, 128, 16, 128, 8, 0, 1>(b0wih, b0whh, b0bih, b0bhh, lnbuf,
        y0, 128, 0, bid, 0, nullptr, nullptr, flg + 1536 + bid * 16, sm);
  } else {
    const int g = bid - 8;
    gruB1_scan(b1wih, b1whh, b1bih, b1bhh, h0f, y0, ln1g, ln1b,
               y1, flg + 1536 + g * 16, g, sm);
  }
}

// x -> bf16 full / ::2 / ::4 copies, plus upsample-folded d0 weight
__global__ void __launch_bounds__(256) prep(const float* __restrict__ x,
    u16* __restrict__ xb, u16* __restrict__ xd2, u16* __restrict__ xd4,
    const float* __restrict__ d0w, u16* __restrict__ d0wf) {
  const int b = blockIdx.x;
  if (b < 16384) {
    const long t = b * 256L + threadIdx.x;
    const f4 aa = ((const f4*)x)[t * 2];
    const f4 cc = ((const f4*)x)[t * 2 + 1];
    const u16 u0 = f2bf(aa[0]), u1 = f2bf(aa[1]), u2 = f2bf(aa[2]), u3 = f2bf(aa[3]);
    const u16 u4 = f2bf(cc[0]), u5 = f2bf(cc[1]), u6 = f2bf(cc[2]), u7 = f2bf(cc[3]);
    short8 s8; s8[0]=(short)u0; s8[1]=(short)u1; s8[2]=(short)u2; s8[3]=(short)u3;
    s8[4]=(short)u4; s8[5]=(short)u5; s8[6]=(short)u6; s8[7]=(short)u7;
    *(short8*)(xb + t * 8) = s8;
    const long row = t >> 5; const int ch = (int)(t & 31);
    *(u32*)(xd2 + row * 128 + ch * 4)     = (u32)u0 | ((u32)u2 << 16);
    *(u32*)(xd2 + row * 128 + ch * 4 + 2) = (u32)u4 | ((u32)u6 << 16);
    *(u32*)(xd4 + row * 64 + ch * 2)      = (u32)u0 | ((u32)u4 << 16);
  } else {
    const int idx = (b - 16384) * 256 + threadIdx.x;
    const int o = idx / 896, c = idx % 896;
    float v;
    if (c < 512) v = d0w[o * 1536 + c];
    else if (c < 768) { const int j = c - 512; v = d0w[o * 1536 + 512 + 2 * j] + d0w[o * 1536 + 513 + 2 * j]; }
    else { const int j = c - 768; const float* p = d0w + o * 1536 + 1024 + 4 * j; v = p[0] + p[1] + p[2] + p[3]; }
    d0wf[idx] = f2bf(v);
  }
}

// d0 dense: (S*B,896)bf16 @ (128,896)bf16^T + bias, relu -> fp32
__global__ void __launch_bounds__(256) gemm_d0(const u16* __restrict__ A,
    const u16* __restrict__ Bw, const float* __restrict__ bias, float* __restrict__ C) {
  __shared__ __align__(16) u16 sA[128 * 40];
  __shared__ __align__(16) u16 sB[128 * 40];
  const int tid = threadIdx.x, l = tid & 63, wv = tid >> 6;
  const int wm = wv >> 1, wn = wv & 1;
  const long m0 = (long)blockIdx.x * 128;
  f4 acc[4][4] = {};
  const int ra = tid & 127, half = tid >> 7;
  for (int kt = 0; kt < 28; ++kt) {
    const u16* gA = A + (m0 + ra) * 896 + kt * 32 + half * 16;
    const u16* gB = Bw + (long)ra * 896 + kt * 32 + half * 16;
    const short8 va0 = *(const short8*)(gA);
    const short8 va1 = *(const short8*)(gA + 8);
    const short8 vb0 = *(const short8*)(gB);
    const short8 vb1 = *(const short8*)(gB + 8);
    __syncthreads();
    *(short8*)(sA + ra * 40 + half * 16)     = va0;
    *(short8*)(sA + ra * 40 + half * 16 + 8) = va1;
    *(short8*)(sB + ra * 40 + half * 16)     = vb0;
    *(short8*)(sB + ra * 40 + half * 16 + 8) = vb1;
    __syncthreads();
    short8 af[4], bfv[4];
#pragma unroll
    for (int i = 0; i < 4; ++i) {
      af[i]  = *(const short8*)(sA + (wm * 64 + i * 16 + (l & 15)) * 40 + (l >> 4) * 8);
      bfv[i] = *(const short8*)(sB + (wn * 64 + i * 16 + (l & 15)) * 40 + (l >> 4) * 8);
    }
#pragma unroll
    for (int i = 0; i < 4; ++i)
#pragma unroll
      for (int j = 0; j < 4; ++j)
        acc[i][j] = MFMA16(af[i], bfv[j], acc[i][j], 0, 0, 0);
  }
#pragma unroll
  for (int i = 0; i < 4; ++i) {
    const int m = wm * 64 + i * 16 + (l >> 4) * 4;
#pragma unroll
    for (int j = 0; j < 4; ++j) {
      const int n = wn * 64 + j * 16 + (l & 15);
      const float bs = bias[n];
#pragma unroll
      for (int q = 0; q < 4; ++q) {
        const float v = acc[i][j][q] + bs;
        C[(m0 + m + q) * 128 + n] = v > 0.f ? v : 0.f;
      }
    }
  }
}

// LayerNorm over 128 (LN0 only)
template<bool RESID>
__global__ void __launch_bounds__(256) ln_k(const float* __restrict__ hin,
    const u16* __restrict__ yin, const float* __restrict__ g, const float* __restrict__ b,
    u16* __restrict__ lnout, float* __restrict__ hout) {
  const long row = blockIdx.x * 4L + (threadIdx.x >> 6);
  const int l = threadIdx.x & 63;
  float vx = hin[row * 128 + l * 2], vy = hin[row * 128 + l * 2 + 1];
  if constexpr (RESID) {
    const u32 yp = *(const u32*)(yin + row * 128 + l * 2);
    vx += bf2f(yp & 0xffffu); vy += bf2f(yp >> 16);
    float2 w = {vx, vy};
    *(float2*)(hout + row * 128 + l * 2) = w;
  }
  float s1 = vx + vy, s2 = vx * vx + vy * vy;
#pragma unroll
  for (int o = 1; o < 64; o <<= 1) { s1 += __shfl_xor(s1, o); s2 += __shfl_xor(s2, o); }
  const float m = s1 * 0.0078125f;
  const float rs = rsqrtf(s2 * 0.0078125f - m * m + 1e-5f);
  const float o0 = (vx - m) * rs * g[l * 2] + b[l * 2];
  const float o1 = (vy - m) * rs * g[l * 2 + 1] + b[l * 2 + 1];
  *(u32*)(lnout + row * 128 + l * 2) = (u32)f2bf(o0) | ((u32)f2bf(o1) << 16);
}

// out = (h0 + y0 + y1) @ df_w^T + df_b  (full fp32)
__global__ void __launch_bounds__(256) final_k(const float* __restrict__ h0,
    const u16* __restrict__ y0, const u16* __restrict__ y1,
    const float* __restrict__ w, const float* __restrict__ wb,
    float* __restrict__ out) {
  __shared__ float sw[512];
  __shared__ float sb[4];
  if (threadIdx.x < 4) sb[threadIdx.x] = wb[threadIdx.x];
  for (int i = threadIdx.x; i < 512; i += 256) sw[i] = w[i];
  __syncthreads();
  const long row = blockIdx.x * 256L + threadIdx.x;
  float a0 = sb[0], a1 = sb[1], a2 = sb[2], a3 = sb[3];
  const float* hr = h0 + row * 128;
  const u16* yr0 = y0 + row * 128;
  const u16* yr1 = y1 + row * 128;
#pragma unroll 4
  for (int c = 0; c < 128; c += 4) {
    const f4 hv = *(const f4*)(hr + c);
    const u32 p0 = *(const u32*)(yr0 + c);
    const u32 p1 = *(const u32*)(yr0 + c + 2);
    const u32 q0 = *(const u32*)(yr1 + c);
    const u32 q1 = *(const u32*)(yr1 + c + 2);
    const float v0 = hv[0] + bf2f(p0 & 0xffffu) + bf2f(q0 & 0xffffu);
    const float v1 = hv[1] + bf2f(p0 >> 16)     + bf2f(q0 >> 16);
    const float v2 = hv[2] + bf2f(p1 & 0xffffu) + bf2f(q1 & 0xffffu);
    const float v3 = hv[3] + bf2f(p1 >> 16)     + bf2f(q1 >> 16);
    a0 += v0 * sw[c]       + v1 * sw[c + 1]       + v2 * sw[c + 2]       + v3 * sw[c + 3];
    a1 += v0 * sw[128 + c] + v1 * sw[128 + c + 1] + v2 * sw[128 + c + 2] + v3 * sw[128 + c + 3];
    a2 += v0 * sw[256 + c] + v1 * sw[256 + c + 1] + v2 * sw[256 + c + 2] + v3 * sw[256 + c + 3];
    a3 += v0 * sw[384 + c] + v1 * sw[384 + c + 1] + v2 * sw[384 + c + 2] + v3 * sw[384 + c + 3];
  }
  f4 o = {a0, a1, a2, a3};
  *(f4*)(out + row * 4) = o;
}

extern "C" void kernel_launch(void* const* d_in, const int* in_sizes, int n_in,
                              void* d_out, int out_size, void* d_ws, size_t ws_size,
                              hipStream_t stream) {
  char* ws = (char*)d_ws;
  const float* x     = (const float*)d_in[0];
  const float* g0wih = (const float*)d_in[1];
  const float* g0whh = (const float*)d_in[2];
  const float* g0bih = (const float*)d_in[3];
  const float* g0bhh = (const float*)d_in[4];
  const float* g1wih = (const float*)d_in[5];
  const float* g1whh = (const float*)d_in[6];
  const float* g1bih = (const float*)d_in[7];
  const float* g1bhh = (const float*)d_in[8];
  const float* g2wih = (const float*)d_in[9];
  const float* g2whh = (const float*)d_in[10];
  const float* g2bih = (const float*)d_in[11];
  const float* g2bhh = (const float*)d_in[12];
  const float* d0w   = (const float*)d_in[13];
  const float* d0b   = (const float*)d_in[14];
  const float* ln0g  = (const float*)d_in[15];
  const float* ln0b  = (const float*)d_in[16];
  const float* b0wih = (const float*)d_in[17];
  const float* b0whh = (const float*)d_in[18];
  const float* b0bih = (const float*)d_in[19];
  const float* b0bhh = (const float*)d_in[20];
  const float* ln1g  = (const float*)d_in[21];
  const float* ln1b  = (const float*)d_in[22];
  const float* b1wih = (const float*)d_in[23];
  const float* b1whh = (const float*)d_in[24];
  const float* b1bih = (const float*)d_in[25];
  const float* b1bhh = (const float*)d_in[26];
  const float* dfw   = (const float*)d_in[27];
  const float* dfb   = (const float*)d_in[28];

  u16* xb    = (u16*)(ws + OFF_XB);
  u16* xd2   = (u16*)(ws + OFF_XD2);
  u16* xd4   = (u16*)(ws + OFF_XD4);
  u16* hcat  = (u16*)(ws + OFF_HCAT);
  u16* y0    = (u16*)(ws + OFF_Y);
  u16* y1    = (u16*)(ws + OFF_H1);
  u16* d0wf  = (u16*)(ws + OFF_D0WF);
  u32* hbuf0 = (u32*)(ws + OFF_HB0);
  u32* hbuf1 = (u32*)(ws + OFF_HB1);
  u32* flg   = (u32*)(ws + OFF_FLG);
  // phase aliases (x buffers are dead after scanA)
  float* h0f = (float*)(ws + OFF_XB);
  u16* lnbuf = (u16*)(ws + OFF_XD2);

  // reset h broadcast buffers + flags (h0 = 0, flags = 0)
  hipMemsetAsync(ws + OFF_HB0, 0, (size_t)(OFF_FLG + 16384 - OFF_HB0), stream);

  prep<<<16832, 256, 0, stream>>>(x, xb, xd2, xd4, d0w, d0wf);

  ScanAArgs sa;
  sa.w0ih = g0wih; sa.w0hh = g0whh; sa.b0ih = g0bih; sa.b0hh = g0bhh;
  sa.w1ih = g1wih; sa.w1hh = g1whh; sa.b1ih = g1bih; sa.b1hh = g1bhh;
  sa.w2ih = g2wih; sa.w2hh = g2whh; sa.b2ih = g2bih; sa.b2hh = g2bhh;
  sa.xb = xb; sa.xd2 = xd2; sa.xd4 = xd4;
  sa.hcat = hcat; sa.hbuf0 = hbuf0; sa.hbuf1 = hbuf1; sa.flg = flg;
  scanA<<<104, 512, 0, stream>>>(sa);

  gemm_d0<<<1024, 256, 0, stream>>>(hcat, d0wf, d0b, h0f);

  ln_k<false><<<32768, 256, 0, stream>>>(h0f, nullptr, ln0g, ln0b, lnbuf, nullptr);

  scanB2<<<16, 512, 0, stream>>>(b0wih, b0whh, b0bih, b0bhh,
                                 b1wih, b1whh, b1bih, b1bhh,
                                 lnbuf, h0f, ln1g, ln1b, y0, y1, flg);

  final_k<<<512, 256, 0, stream>>>(h0f, y0, y1, dfw, dfb, (float*)d_out);
}